// Round 5
// baseline (369.352 us; speedup 1.0000x reference)
//
#include <hip/hip_runtime.h>
#include <hip/hip_bf16.h>

#define B_ 32
#define T_ 4096
#define H_ 512
#define A_ 512
#define C_ 32
#define KTOT 544            // H + C (conv folded in as K-extension)
#define NKG  (KTOT / 8)     // 68 k-groups of 8
#define NKS  (KTOT / 32)    // 17 MFMA k-steps
#define TT   64             // t-tile rows per block

typedef float f32x4 __attribute__((ext_vector_type(4)));
typedef __bf16 bf16x8 __attribute__((ext_vector_type(8)));

__device__ inline float fast_tanh(float x) {
    // tanh(x) = 1 - 2/(exp(2x)+1); exact at saturation, |err| ~1e-7
    float t = __expf(2.0f * x);
    return 1.0f - 2.0f / (t + 1.0f);
}

// ---------------- prep: dpb = dec@W^T + b ; V,U -> unified bf16 fragment buffer ----
// Vsall[(k>>3)*A + a]*8 + (k&7), k in [0,544): k<512 from V, k>=512 from U.
__global__ __launch_bounds__(256) void prep_kernel(
    const float* __restrict__ dec, const float* __restrict__ W,
    const float* __restrict__ bvec, const float* __restrict__ V,
    const float* __restrict__ U,
    float* __restrict__ dpb, __bf16* __restrict__ Vsall) {
    int id = blockIdx.x * 256 + threadIdx.x;
    const int N1 = B_ * A_;          // 16384
    const int N2 = A_ * H_;          // 262144
    if (id < N1) {
        int b = id / A_, a = id % A_;
        const float* dr = dec + b * H_;
        const float* wr = W + (size_t)a * H_;
        float s = 0.f;
        #pragma unroll 8
        for (int h = 0; h < H_; ++h) s += dr[h] * wr[h];
        dpb[id] = s + bvec[a];
    } else if (id < N1 + N2) {
        int e = id - N1;
        int a = e >> 9, k = e & 511;
        Vsall[((k >> 3) * A_ + a) * 8 + (k & 7)] = (__bf16)V[(size_t)a * H_ + k];
    } else {
        int e = id - N1 - N2;        // 16384 U elements
        int a = e >> 5, c = e & 31;
        int k = H_ + c;
        Vsall[((k >> 3) * A_ + a) * 8 + (k & 7)] = (__bf16)U[a * C_ + c];
    }
}

// ---------------- fused scores: MFMA bf16, 64-row t-tile, 8 waves ----------------
// wave wid: wh = wid>>2 picks t-half (32 rows), wq = wid&3 picks 128-col quarter.
__global__ __launch_bounds__(512) void scores_mfma(
    const float* __restrict__ enc, const float* __restrict__ align,
    const float* __restrict__ conv_w, const float* __restrict__ conv_b,
    const __bf16* __restrict__ Vsall, const float* __restrict__ dpb,
    const float* __restrict__ wvec, float* __restrict__ scores) {
    const int t0 = blockIdx.x * TT;
    const int b  = blockIdx.y;
    const int tid = threadIdx.x;
    const int lane = tid & 63, wid = tid >> 6;
    const int row0 = lane & 15;   // C/D col lane (a-col within 16)
    const int kg   = lane >> 4;   // k-group 0..3 within a 32-k step
    const int wq   = wid & 3;     // A-col quarter
    const int wh   = wid >> 2;    // t-half (sub-tile index s)
    const int wcol = wq * 128;

    // fragment f = (kgidx*2 + row/32)*32 + row%32, stored at g = f ^ (kgidx&7)
    __shared__ __bf16 Ebf[NKG * TT * 8];   // 69632 B
    __shared__ float spart[4][TT];

    // --- stage encoder rows (64 x 512 fp32 -> bf16 fragments) ---
    const float* encb = enc + ((size_t)b * T_ + t0) * H_;
    #pragma unroll
    for (int it = 0; it < 8; ++it) {
        int u = it * 512 + tid;            // unit = row*64 + kgidx, kgidx<64
        int row = u >> 6;
        int kgidx = u & 63;
        const float* p = encb + row * H_ + kgidx * 8;
        f32x4 lo = *reinterpret_cast<const f32x4*>(p);
        f32x4 hi = *reinterpret_cast<const f32x4*>(p + 4);
        bf16x8 v;
        v[0] = (__bf16)lo.x; v[1] = (__bf16)lo.y; v[2] = (__bf16)lo.z; v[3] = (__bf16)lo.w;
        v[4] = (__bf16)hi.x; v[5] = (__bf16)hi.y; v[6] = (__bf16)hi.z; v[7] = (__bf16)hi.w;
        int f = (kgidx * 2 + (row >> 5)) * 32 + (row & 31);
        int g = f ^ (kgidx & 7);
        *reinterpret_cast<bf16x8*>(&Ebf[g * 8]) = v;
    }
    // --- conv_feat rows as k-extension (kgidx 64..67) ---
    if (tid < 256) {
        int row = tid & 63, kq = tid >> 6;
        int kgidx = 64 + kq;
        int t = t0 + row;
        float x0 = (t > 0) ? align[b * T_ + t - 1] : 0.f;
        float x1 = align[b * T_ + t];
        float x2 = (t + 1 < T_) ? align[b * T_ + t + 1] : 0.f;
        bf16x8 v;
        #pragma unroll
        for (int e = 0; e < 8; ++e) {
            int c = kq * 8 + e;
            float val = conv_b[c] + conv_w[c * 3 + 0] * x0 + conv_w[c * 3 + 1] * x1
                                  + conv_w[c * 3 + 2] * x2;
            v[e] = (__bf16)val;
        }
        int f = (kgidx * 2 + (row >> 5)) * 32 + (row & 31);
        int g = f ^ (kgidx & 7);
        *reinterpret_cast<bf16x8*>(&Ebf[g * 8]) = v;
    }
    __syncthreads();

    f32x4 acc[2][8];
    #pragma unroll
    for (int m = 0; m < 2; ++m)
        #pragma unroll
        for (int n = 0; n < 8; ++n) acc[m][n] = (f32x4){0.f, 0.f, 0.f, 0.f};

    // --- K loop with 1-deep register double-buffer on B fragments ---
    bf16x8 bcur[8], bnxt[8];
    {
        const __bf16* vp = Vsall + (size_t)kg * (A_ * 8);
        #pragma unroll
        for (int n = 0; n < 8; ++n)
            bcur[n] = *reinterpret_cast<const bf16x8*>(vp + (wcol + n * 16 + row0) * 8);
    }
    #pragma unroll
    for (int ks = 0; ks < NKS; ++ks) {
        if (ks + 1 < NKS) {
            const __bf16* vp = Vsall + (size_t)((ks + 1) * 4 + kg) * (A_ * 8);
            #pragma unroll
            for (int n = 0; n < 8; ++n)
                bnxt[n] = *reinterpret_cast<const bf16x8*>(vp + (wcol + n * 16 + row0) * 8);
        }
        const int kgidx = ks * 4 + kg;
        bf16x8 afrag[2];
        #pragma unroll
        for (int m = 0; m < 2; ++m) {
            int f = (kgidx * 2 + wh) * 32 + m * 16 + row0;
            int g = f ^ (kgidx & 7);
            afrag[m] = *reinterpret_cast<const bf16x8*>(&Ebf[g * 8]);
        }
        #pragma unroll
        for (int n = 0; n < 8; ++n) {
            acc[0][n] = __builtin_amdgcn_mfma_f32_16x16x32_bf16(afrag[0], bcur[n], acc[0][n], 0, 0, 0);
            acc[1][n] = __builtin_amdgcn_mfma_f32_16x16x32_bf16(afrag[1], bcur[n], acc[1][n], 0, 0, 0);
        }
        #pragma unroll
        for (int n = 0; n < 8; ++n) bcur[n] = bnxt[n];
    }

    // --- epilogue: tanh(acc + dpb)*w, reduce over A ---
    float dval[8], wv[8];
    #pragma unroll
    for (int n = 0; n < 8; ++n) {
        int a = wcol + n * 16 + row0;
        dval[n] = dpb[b * A_ + a];
        wv[n]   = wvec[a];
    }
    #pragma unroll
    for (int m = 0; m < 2; ++m) {
        float rs[4] = {0.f, 0.f, 0.f, 0.f};
        #pragma unroll
        for (int n = 0; n < 8; ++n) {
            #pragma unroll
            for (int j = 0; j < 4; ++j) {
                float x = acc[m][n][j] + dval[n];
                rs[j] += fast_tanh(x) * wv[n];
            }
        }
        #pragma unroll
        for (int j = 0; j < 4; ++j) {
            float v = rs[j];
            v += __shfl_xor(v, 1);
            v += __shfl_xor(v, 2);
            v += __shfl_xor(v, 4);
            v += __shfl_xor(v, 8);
            if (row0 == 0) spart[wq][wh * 32 + m * 16 + kg * 4 + j] = v;
        }
    }
    __syncthreads();
    if (tid < TT) {
        float s = spart[0][tid] + spart[1][tid] + spart[2][tid] + spart[3][tid];
        scores[b * T_ + t0 + tid] = s;
    }
}

// ---------------- softmax over T per batch; fp32 alignment into d_out ----------------
__global__ __launch_bounds__(256) void softmax_k(
    const float* __restrict__ scores, float* __restrict__ out_align) {
    int b = blockIdx.x;
    int tid = threadIdx.x;
    __shared__ float redm[4];
    __shared__ float reds[4];
    float local[16];
    float mx = -1e30f;
    #pragma unroll
    for (int i = 0; i < 16; ++i) {
        float s = scores[b * T_ + tid + i * 256];
        local[i] = s;
        mx = fmaxf(mx, s);
    }
    for (int off = 32; off >= 1; off >>= 1) mx = fmaxf(mx, __shfl_xor(mx, off));
    if ((tid & 63) == 0) redm[tid >> 6] = mx;
    __syncthreads();
    mx = fmaxf(fmaxf(redm[0], redm[1]), fmaxf(redm[2], redm[3]));
    float sum = 0.f;
    #pragma unroll
    for (int i = 0; i < 16; ++i) { local[i] = __expf(local[i] - mx); sum += local[i]; }
    for (int off = 32; off >= 1; off >>= 1) sum += __shfl_xor(sum, off);
    if ((tid & 63) == 0) reds[tid >> 6] = sum;
    __syncthreads();
    sum = reds[0] + reds[1] + reds[2] + reds[3];
    float inv = 1.0f / sum;
    #pragma unroll
    for (int i = 0; i < 16; ++i)
        out_align[b * T_ + tid + i * 256] = local[i] * inv;
}

// ---------------- pout[b,chunk,h] = sum_{t in chunk} alpha * enc ----------------
__global__ __launch_bounds__(512) void pout_k(
    const float* __restrict__ enc, const float* __restrict__ alpha,
    float* __restrict__ pout) {
    int chunk = blockIdx.x;   // 0..7 (512 rows each)
    int b = blockIdx.y;
    int tid = threadIdx.x;
    int t0 = chunk * 512;
    __shared__ float as[512];
    as[tid] = alpha[b * T_ + t0 + tid];
    __syncthreads();
    float acc = 0.f;
    const float* ep = enc + ((size_t)b * T_ + t0) * H_ + tid;
    #pragma unroll 4
    for (int t = 0; t < 512; ++t) acc += as[t] * ep[(size_t)t * H_];
    pout[((size_t)b * 8 + chunk) * H_ + tid] = acc;
}

__global__ __launch_bounds__(512) void combine_k(
    const float* __restrict__ pout, float* __restrict__ out) {
    int b = blockIdx.x; int h = threadIdx.x;
    float s = 0.f;
    #pragma unroll
    for (int c = 0; c < 8; ++c) s += pout[((size_t)b * 8 + c) * H_ + h];
    out[b * H_ + h] = s;
}

extern "C" void kernel_launch(void* const* d_in, const int* in_sizes, int n_in,
                              void* d_out, int out_size, void* d_ws, size_t ws_size,
                              hipStream_t stream) {
    const float* dec    = (const float*)d_in[0];
    const float* enc    = (const float*)d_in[1];
    const float* align  = (const float*)d_in[2];
    const float* conv_w = (const float*)d_in[3];
    const float* conv_b = (const float*)d_in[4];
    const float* W      = (const float*)d_in[5];
    const float* V      = (const float*)d_in[6];
    const float* U      = (const float*)d_in[7];
    const float* bvec   = (const float*)d_in[8];
    const float* wvec   = (const float*)d_in[9];
    float* out       = (float*)d_out;           // output[B,H] fp32
    float* out_align = out + B_ * H_;           // alignment[B,T] fp32

    char* ws = (char*)d_ws;
    float*  dpb    = (float*)(ws);                   // 64 KB
    float*  scores = (float*)(ws + (64 << 10));      // 512 KB
    float*  pout   = (float*)(ws + (576 << 10));     // 512 KB
    __bf16* Vsall  = (__bf16*)(ws + (1088 << 10));   // 544 KB

    prep_kernel<<<(B_ * A_ + A_ * H_ + A_ * C_) / 256, 256, 0, stream>>>(
        dec, W, bvec, V, U, dpb, Vsall);
    scores_mfma<<<dim3(T_ / TT, B_), 512, 0, stream>>>(enc, align, conv_w, conv_b,
                                                       Vsall, dpb, wvec, scores);
    softmax_k<<<B_, 256, 0, stream>>>(scores, out_align);
    pout_k<<<dim3(8, B_), 512, 0, stream>>>(enc, out_align, pout);
    combine_k<<<B_, 512, 0, stream>>>(pout, out);
}

// Round 6
// 265.373 us; speedup vs baseline: 1.3918x; 1.3918x over previous
//
#include <hip/hip_runtime.h>
#include <hip/hip_bf16.h>

#define B_ 32
#define T_ 4096
#define H_ 512
#define A_ 512
#define C_ 32
#define KTOT 544            // H + C (conv folded in as K-extension)
#define NKG  (KTOT / 8)     // 68 k-groups of 8
#define NKS  (KTOT / 32)    // 17 MFMA k-steps
#define TT   64             // t-tile rows per block

typedef float f32x4 __attribute__((ext_vector_type(4)));
typedef __bf16 bf16x8 __attribute__((ext_vector_type(8)));

__device__ inline float fast_tanh(float x) {
    // tanh(x) = 1 - 2/(exp(2x)+1); exact at saturation, |err| ~1e-7
    float t = __expf(2.0f * x);
    return 1.0f - 2.0f / (t + 1.0f);
}

__device__ __forceinline__ void async16(const void* g, void* l) {
    // 16B global -> LDS direct copy (wave-uniform base + lane*16 on LDS side)
    __builtin_amdgcn_global_load_lds(
        (const __attribute__((address_space(1))) unsigned int*)g,
        (__attribute__((address_space(3))) unsigned int*)l, 16, 0, 0);
}

// ---------------- prep: dpb = dec@W^T + b ; V,U -> unified bf16 fragment buffer ----
// Vsall[(k>>3)*A + a]*8 + (k&7), k in [0,544): k<512 from V, k>=512 from U.
// Per k-step chunk (4 kgroups x 512 cols x 8 elems = 32KB) is CONTIGUOUS.
__global__ __launch_bounds__(256) void prep_kernel(
    const float* __restrict__ dec, const float* __restrict__ W,
    const float* __restrict__ bvec, const float* __restrict__ V,
    const float* __restrict__ U,
    float* __restrict__ dpb, __bf16* __restrict__ Vsall) {
    int id = blockIdx.x * 256 + threadIdx.x;
    const int N1 = B_ * A_;          // 16384
    const int N2 = A_ * H_;          // 262144
    if (id < N1) {
        int b = id / A_, a = id % A_;
        const float* dr = dec + b * H_;
        const float* wr = W + (size_t)a * H_;
        float s = 0.f;
        #pragma unroll 8
        for (int h = 0; h < H_; ++h) s += dr[h] * wr[h];
        dpb[id] = s + bvec[a];
    } else if (id < N1 + N2) {
        int e = id - N1;
        int a = e >> 9, k = e & 511;
        Vsall[((k >> 3) * A_ + a) * 8 + (k & 7)] = (__bf16)V[(size_t)a * H_ + k];
    } else {
        int e = id - N1 - N2;        // 16384 U elements
        int a = e >> 5, c = e & 31;
        int k = H_ + c;
        Vsall[((k >> 3) * A_ + a) * 8 + (k & 7)] = (__bf16)U[a * C_ + c];
    }
}

// ---------------- fused scores: MFMA bf16, B staged via global_load_lds dbuf ----
// 8 waves: wq = wid&3 -> 128-col quarter, wh = wid>>2 -> 32-row t-half.
__global__ __launch_bounds__(512) void scores_mfma(
    const float* __restrict__ enc, const float* __restrict__ align,
    const float* __restrict__ conv_w, const float* __restrict__ conv_b,
    const __bf16* __restrict__ Vsall, const float* __restrict__ dpb,
    const float* __restrict__ wvec, float* __restrict__ scores) {
    const int t0 = blockIdx.x * TT;
    const int b  = blockIdx.y;
    const int tid = threadIdx.x;
    const int lane = tid & 63, wid = tid >> 6;
    const int row0 = lane & 15;   // C/D col lane (a-col within 16)
    const int kg   = lane >> 4;   // k-group 0..3 within a 32-k step
    const int wq   = wid & 3;     // A-col quarter
    const int wh   = wid >> 2;    // t-half
    const int wcol = wq * 128;

    __shared__ __bf16 Ebf[NKG * TT * 8];   // 69632 B, swizzled A fragments
    __shared__ __bf16 Bts[2][4 * A_ * 8];  // 2 x 32768 B, B k-step tiles
    __shared__ float spart[4][TT];

    // --- stage B k-step 0 (async, drains at the barrier below) ---
    {
        const __bf16* vchunk = Vsall;      // kstep 0 chunk
        #pragma unroll
        for (int i = 0; i < 4; ++i) {
            int u = i * 512 + tid;         // 16B unit index, linear both sides
            async16(vchunk + u * 8, &Bts[0][u * 8]);
        }
    }

    // --- stage encoder rows (64 x 512 fp32 -> bf16 fragments, swizzled) ---
    const float* encb = enc + ((size_t)b * T_ + t0) * H_;
    #pragma unroll
    for (int it = 0; it < 8; ++it) {
        int u = it * 512 + tid;            // u = row*64 + kgidx
        int row = u >> 6;
        int kgidx = u & 63;
        const float* p = encb + row * H_ + kgidx * 8;
        f32x4 lo = *reinterpret_cast<const f32x4*>(p);
        f32x4 hi = *reinterpret_cast<const f32x4*>(p + 4);
        bf16x8 v;
        v[0] = (__bf16)lo.x; v[1] = (__bf16)lo.y; v[2] = (__bf16)lo.z; v[3] = (__bf16)lo.w;
        v[4] = (__bf16)hi.x; v[5] = (__bf16)hi.y; v[6] = (__bf16)hi.z; v[7] = (__bf16)hi.w;
        int f = (kgidx * 2 + (row >> 5)) * 32 + (row & 31);
        int g = f ^ (kgidx & 7);
        *reinterpret_cast<bf16x8*>(&Ebf[g * 8]) = v;
    }
    // --- conv_feat rows as k-extension (kgidx 64..67) ---
    if (tid < 256) {
        int row = tid & 63, kq = tid >> 6;
        int kgidx = 64 + kq;
        int t = t0 + row;
        float x0 = (t > 0) ? align[b * T_ + t - 1] : 0.f;
        float x1 = align[b * T_ + t];
        float x2 = (t + 1 < T_) ? align[b * T_ + t + 1] : 0.f;
        bf16x8 v;
        #pragma unroll
        for (int e = 0; e < 8; ++e) {
            int c = kq * 8 + e;
            float val = conv_b[c] + conv_w[c * 3 + 0] * x0 + conv_w[c * 3 + 1] * x1
                                  + conv_w[c * 3 + 2] * x2;
            v[e] = (__bf16)val;
        }
        int f = (kgidx * 2 + (row >> 5)) * 32 + (row & 31);
        int g = f ^ (kgidx & 7);
        *reinterpret_cast<bf16x8*>(&Ebf[g * 8]) = v;
    }
    __syncthreads();   // drains A stores + kstep0 async loads

    f32x4 acc[2][8];
    #pragma unroll
    for (int m = 0; m < 2; ++m)
        #pragma unroll
        for (int n = 0; n < 8; ++n) acc[m][n] = (f32x4){0.f, 0.f, 0.f, 0.f};

    int cur = 0;
    for (int ks = 0; ks < NKS; ++ks) {
        // issue next k-step's B stage into the other buffer (overlaps compute)
        if (ks + 1 < NKS) {
            const __bf16* vchunk = Vsall + (size_t)(ks + 1) * (4 * A_ * 8);
            __bf16* ldst = &Bts[cur ^ 1][0];
            #pragma unroll
            for (int i = 0; i < 4; ++i) {
                int u = i * 512 + tid;
                async16(vchunk + u * 8, ldst + u * 8);
            }
        }
        // compute current k-step from Bts[cur] + Ebf
        const int kgidx = ks * 4 + kg;
        bf16x8 afrag[2];
        #pragma unroll
        for (int m = 0; m < 2; ++m) {
            int f = (kgidx * 2 + wh) * 32 + m * 16 + row0;
            int g = f ^ (kgidx & 7);
            afrag[m] = *reinterpret_cast<const bf16x8*>(&Ebf[g * 8]);
        }
        const __bf16* bp = &Bts[cur][kg * (A_ * 8)];
        #pragma unroll
        for (int n = 0; n < 8; ++n) {
            bf16x8 bfrag = *reinterpret_cast<const bf16x8*>(bp + (wcol + n * 16 + row0) * 8);
            acc[0][n] = __builtin_amdgcn_mfma_f32_16x16x32_bf16(afrag[0], bfrag, acc[0][n], 0, 0, 0);
            acc[1][n] = __builtin_amdgcn_mfma_f32_16x16x32_bf16(afrag[1], bfrag, acc[1][n], 0, 0, 0);
        }
        __syncthreads();   // drains async loads (next tile ready) + all reads of cur
        cur ^= 1;
    }

    // --- epilogue: tanh(acc + dpb)*w, reduce over A ---
    float dval[8], wv[8];
    #pragma unroll
    for (int n = 0; n < 8; ++n) {
        int a = wcol + n * 16 + row0;
        dval[n] = dpb[b * A_ + a];
        wv[n]   = wvec[a];
    }
    #pragma unroll
    for (int m = 0; m < 2; ++m) {
        float rs[4] = {0.f, 0.f, 0.f, 0.f};
        #pragma unroll
        for (int n = 0; n < 8; ++n) {
            #pragma unroll
            for (int j = 0; j < 4; ++j) {
                float x = acc[m][n][j] + dval[n];
                rs[j] += fast_tanh(x) * wv[n];
            }
        }
        #pragma unroll
        for (int j = 0; j < 4; ++j) {
            float v = rs[j];
            v += __shfl_xor(v, 1);
            v += __shfl_xor(v, 2);
            v += __shfl_xor(v, 4);
            v += __shfl_xor(v, 8);
            if (row0 == 0) spart[wq][wh * 32 + m * 16 + kg * 4 + j] = v;
        }
    }
    __syncthreads();
    if (tid < TT) {
        float s = spart[0][tid] + spart[1][tid] + spart[2][tid] + spart[3][tid];
        scores[b * T_ + t0 + tid] = s;
    }
}

// ---------------- softmax over T per batch; fp32 alignment into d_out ----------------
__global__ __launch_bounds__(256) void softmax_k(
    const float* __restrict__ scores, float* __restrict__ out_align) {
    int b = blockIdx.x;
    int tid = threadIdx.x;
    __shared__ float redm[4];
    __shared__ float reds[4];
    float local[16];
    float mx = -1e30f;
    #pragma unroll
    for (int i = 0; i < 16; ++i) {
        float s = scores[b * T_ + tid + i * 256];
        local[i] = s;
        mx = fmaxf(mx, s);
    }
    for (int off = 32; off >= 1; off >>= 1) mx = fmaxf(mx, __shfl_xor(mx, off));
    if ((tid & 63) == 0) redm[tid >> 6] = mx;
    __syncthreads();
    mx = fmaxf(fmaxf(redm[0], redm[1]), fmaxf(redm[2], redm[3]));
    float sum = 0.f;
    #pragma unroll
    for (int i = 0; i < 16; ++i) { local[i] = __expf(local[i] - mx); sum += local[i]; }
    for (int off = 32; off >= 1; off >>= 1) sum += __shfl_xor(sum, off);
    if ((tid & 63) == 0) reds[tid >> 6] = sum;
    __syncthreads();
    sum = reds[0] + reds[1] + reds[2] + reds[3];
    float inv = 1.0f / sum;
    #pragma unroll
    for (int i = 0; i < 16; ++i)
        out_align[b * T_ + tid + i * 256] = local[i] * inv;
}

// ---------------- pout[b,chunk,h] = sum_{t in chunk} alpha * enc ----------------
__global__ __launch_bounds__(512) void pout_k(
    const float* __restrict__ enc, const float* __restrict__ alpha,
    float* __restrict__ pout) {
    int chunk = blockIdx.x;   // 0..7 (512 rows each)
    int b = blockIdx.y;
    int tid = threadIdx.x;
    int t0 = chunk * 512;
    __shared__ float as[512];
    as[tid] = alpha[b * T_ + t0 + tid];
    __syncthreads();
    float acc = 0.f;
    const float* ep = enc + ((size_t)b * T_ + t0) * H_ + tid;
    #pragma unroll 4
    for (int t = 0; t < 512; ++t) acc += as[t] * ep[(size_t)t * H_];
    pout[((size_t)b * 8 + chunk) * H_ + tid] = acc;
}

__global__ __launch_bounds__(512) void combine_k(
    const float* __restrict__ pout, float* __restrict__ out) {
    int b = blockIdx.x; int h = threadIdx.x;
    float s = 0.f;
    #pragma unroll
    for (int c = 0; c < 8; ++c) s += pout[((size_t)b * 8 + c) * H_ + h];
    out[b * H_ + h] = s;
}

extern "C" void kernel_launch(void* const* d_in, const int* in_sizes, int n_in,
                              void* d_out, int out_size, void* d_ws, size_t ws_size,
                              hipStream_t stream) {
    const float* dec    = (const float*)d_in[0];
    const float* enc    = (const float*)d_in[1];
    const float* align  = (const float*)d_in[2];
    const float* conv_w = (const float*)d_in[3];
    const float* conv_b = (const float*)d_in[4];
    const float* W      = (const float*)d_in[5];
    const float* V      = (const float*)d_in[6];
    const float* U      = (const float*)d_in[7];
    const float* bvec   = (const float*)d_in[8];
    const float* wvec   = (const float*)d_in[9];
    float* out       = (float*)d_out;           // output[B,H] fp32
    float* out_align = out + B_ * H_;           // alignment[B,T] fp32

    char* ws = (char*)d_ws;
    float*  dpb    = (float*)(ws);                   // 64 KB
    float*  scores = (float*)(ws + (64 << 10));      // 512 KB
    float*  pout   = (float*)(ws + (576 << 10));     // 512 KB
    __bf16* Vsall  = (__bf16*)(ws + (1088 << 10));   // 544 KB

    prep_kernel<<<(B_ * A_ + A_ * H_ + A_ * C_) / 256, 256, 0, stream>>>(
        dec, W, bvec, V, U, dpb, Vsall);
    scores_mfma<<<dim3(T_ / TT, B_), 512, 0, stream>>>(enc, align, conv_w, conv_b,
                                                       Vsall, dpb, wvec, scores);
    softmax_k<<<B_, 256, 0, stream>>>(scores, out_align);
    pout_k<<<dim3(8, B_), 512, 0, stream>>>(enc, out_align, pout);
    combine_k<<<B_, 512, 0, stream>>>(pout, out);
}

// Round 8
// 203.330 us; speedup vs baseline: 1.8165x; 1.3051x over previous
//
#include <hip/hip_runtime.h>
#include <hip/hip_bf16.h>

#define B_ 32
#define T_ 4096
#define H_ 512
#define A_ 512
#define C_ 32
#define KTOT 544            // H + C (conv folded in as K-extension)
#define NKS  (KTOT / 32)    // 17 MFMA k-steps
#define TT   128            // t-tile rows per block

typedef float f32x4 __attribute__((ext_vector_type(4)));
typedef __bf16 bf16x8 __attribute__((ext_vector_type(8)));

__device__ inline float fast_tanh(float x) {
    // tanh(x) = 1 - 2/(exp(2x)+1); exact at saturation, |err| ~1e-7
    float t = __expf(2.0f * x);
    return 1.0f - 2.0f / (t + 1.0f);
}

__device__ __forceinline__ void async16(const void* g, void* l) {
    __builtin_amdgcn_global_load_lds(
        (const __attribute__((address_space(1))) unsigned int*)g,
        (__attribute__((address_space(3))) unsigned int*)l, 16, 0, 0);
}

// ---------------- prep: dpb = dec@W^T + b ; V,U -> unified bf16 fragment buffer ----
// Vsall[(k>>3)*A + a]*8 + (k&7), k in [0,544). Per-kstep 32KB chunk contiguous.
__global__ __launch_bounds__(256) void prep_kernel(
    const float* __restrict__ dec, const float* __restrict__ W,
    const float* __restrict__ bvec, const float* __restrict__ V,
    const float* __restrict__ U,
    float* __restrict__ dpb, __bf16* __restrict__ Vsall) {
    int id = blockIdx.x * 256 + threadIdx.x;
    const int N1 = B_ * A_;          // 16384
    const int N2 = A_ * H_;          // 262144
    if (id < N1) {
        int b = id / A_, a = id % A_;
        const float* dr = dec + b * H_;
        const float* wr = W + (size_t)a * H_;
        float s = 0.f;
        #pragma unroll 8
        for (int h = 0; h < H_; ++h) s += dr[h] * wr[h];
        dpb[id] = s + bvec[a];
    } else if (id < N1 + N2) {
        int e = id - N1;
        int a = e >> 9, k = e & 511;
        Vsall[((k >> 3) * A_ + a) * 8 + (k & 7)] = (__bf16)V[(size_t)a * H_ + k];
    } else {
        int e = id - N1 - N2;        // 16384 U elements
        int a = e >> 5, c = e & 31;
        int k = H_ + c;
        Vsall[((k >> 3) * A_ + a) * 8 + (k & 7)] = (__bf16)U[a * C_ + c];
    }
}

// ---------------- fused scores: 128x512 tile, dual-dbuf, 16 waves ----------------
// wave wid: wq = wid&3 -> 128-col quarter, wr = wid>>2 -> 32-row quarter.
// A LDS unit u = row*4 + kgl, swizzled g = u ^ ((u>>4)&7), 16B units.
__global__ __launch_bounds__(1024) void scores_mfma(
    const float* __restrict__ enc, const float* __restrict__ align,
    const float* __restrict__ conv_w, const float* __restrict__ conv_b,
    const __bf16* __restrict__ Vsall, const float* __restrict__ dpb,
    const float* __restrict__ wvec, float* __restrict__ scores) {
    const int t0 = blockIdx.x * TT;
    const int b  = blockIdx.y;
    const int tid = threadIdx.x;
    const int lane = tid & 63, wid = tid >> 6;
    const int row0 = lane & 15;   // C/D col lane
    const int kg   = lane >> 4;   // k-group 0..3 within the 32-k step
    const int wq   = wid & 3;     // col quarter
    const int wr   = wid >> 2;    // row quarter (32 rows)
    const int wcol = wq * 128;

    __shared__ char smem[81920];
    float* spart = (float*)smem;   // [4][TT], aliases A buffers after the loop

    const float* encb = enc + ((size_t)b * T_ + t0) * H_;
    const int arow = tid >> 2, akgl = tid & 3;   // A staging assignment (tid<512)

    // ---- stage kstep 0 ----
    {
        __bf16* bdst = (__bf16*)(smem + 16384);
        #pragma unroll
        for (int i = 0; i < 2; ++i) {
            int u = i * 1024 + tid;
            async16(Vsall + u * 8, bdst + u * 8);
        }
    }
    if (tid < 512) {
        const float* p = encb + arow * H_ + akgl * 8;
        f32x4 lo = *reinterpret_cast<const f32x4*>(p);
        f32x4 hi = *reinterpret_cast<const f32x4*>(p + 4);
        bf16x8 v;
        v[0] = (__bf16)lo.x; v[1] = (__bf16)lo.y; v[2] = (__bf16)lo.z; v[3] = (__bf16)lo.w;
        v[4] = (__bf16)hi.x; v[5] = (__bf16)hi.y; v[6] = (__bf16)hi.z; v[7] = (__bf16)hi.w;
        int g = tid ^ ((tid >> 4) & 7);
        *reinterpret_cast<bf16x8*>((__bf16*)smem + g * 8) = v;
    }
    __syncthreads();

    f32x4 acc[2][8];
    #pragma unroll
    for (int m = 0; m < 2; ++m)
        #pragma unroll
        for (int n = 0; n < 8; ++n) acc[m][n] = (f32x4){0.f, 0.f, 0.f, 0.f};

    int cur = 0;
    for (int ks = 0; ks < NKS; ++ks) {
        __bf16* Acur = (__bf16*)(smem + (cur ? 8192 : 0));
        __bf16* Anxt = (__bf16*)(smem + (cur ? 0 : 8192));
        __bf16* Bcur = (__bf16*)(smem + 16384 + (cur ? 32768 : 0));
        __bf16* Bnxt = (__bf16*)(smem + 16384 + (cur ? 0 : 32768));

        f32x4 alo, ahi;
        bool stage = (ks + 1 < NKS);
        bool conv_step = (ks + 1 == NKS - 1);
        if (stage) {
            // B: async direct to LDS
            const __bf16* vchunk = Vsall + (size_t)(ks + 1) * (4 * A_ * 8);
            #pragma unroll
            for (int i = 0; i < 2; ++i) {
                int u = i * 1024 + tid;
                async16(vchunk + u * 8, Bnxt + u * 8);
            }
            // A: global -> regs (issue early; consumed after compute)
            if (tid < 512 && !conv_step) {
                const float* p = encb + arow * H_ + (ks + 1) * 32 + akgl * 8;
                alo = *reinterpret_cast<const f32x4*>(p);
                ahi = *reinterpret_cast<const f32x4*>(p + 4);
            }
        }

        // ---- compute current k-step ----
        bf16x8 afrag[2];
        #pragma unroll
        for (int m = 0; m < 2; ++m) {
            int row = wr * 32 + m * 16 + row0;
            int u = row * 4 + kg;
            int g = u ^ ((u >> 4) & 7);
            afrag[m] = *reinterpret_cast<const bf16x8*>(Acur + g * 8);
        }
        const __bf16* bp = Bcur + kg * (A_ * 8);
        #pragma unroll
        for (int n = 0; n < 8; ++n) {
            bf16x8 bfrag = *reinterpret_cast<const bf16x8*>(bp + (wcol + n * 16 + row0) * 8);
            acc[0][n] = __builtin_amdgcn_mfma_f32_16x16x32_bf16(afrag[0], bfrag, acc[0][n], 0, 0, 0);
            acc[1][n] = __builtin_amdgcn_mfma_f32_16x16x32_bf16(afrag[1], bfrag, acc[1][n], 0, 0, 0);
        }

        // ---- write A-next to LDS ----
        if (stage && tid < 512) {
            bf16x8 v;
            if (!conv_step) {
                v[0] = (__bf16)alo.x; v[1] = (__bf16)alo.y; v[2] = (__bf16)alo.z; v[3] = (__bf16)alo.w;
                v[4] = (__bf16)ahi.x; v[5] = (__bf16)ahi.y; v[6] = (__bf16)ahi.z; v[7] = (__bf16)ahi.w;
            } else {
                // conv_feat k-extension: k = 512 + akgl*8 + e  ->  channel c
                int t = t0 + arow;
                float x0 = (t > 0) ? align[b * T_ + t - 1] : 0.f;
                float x1 = align[b * T_ + t];
                float x2 = (t + 1 < T_) ? align[b * T_ + t + 1] : 0.f;
                #pragma unroll
                for (int e = 0; e < 8; ++e) {
                    int c = akgl * 8 + e;
                    v[e] = (__bf16)(conv_b[c] + conv_w[c * 3 + 0] * x0
                                  + conv_w[c * 3 + 1] * x1 + conv_w[c * 3 + 2] * x2);
                }
            }
            int g = tid ^ ((tid >> 4) & 7);
            *reinterpret_cast<bf16x8*>(Anxt + g * 8) = v;
        }
        __syncthreads();   // drains B async + A ds_writes; releases cur
        cur ^= 1;
    }

    // ---- epilogue: tanh(acc + dpb)*w, reduce over A ----
    float dval[8], wv[8];
    #pragma unroll
    for (int n = 0; n < 8; ++n) {
        int a = wcol + n * 16 + row0;
        dval[n] = dpb[b * A_ + a];
        wv[n]   = wvec[a];
    }
    #pragma unroll
    for (int m = 0; m < 2; ++m) {
        float rs[4] = {0.f, 0.f, 0.f, 0.f};
        #pragma unroll
        for (int n = 0; n < 8; ++n) {
            #pragma unroll
            for (int j = 0; j < 4; ++j) {
                float x = acc[m][n][j] + dval[n];
                rs[j] += fast_tanh(x) * wv[n];
            }
        }
        #pragma unroll
        for (int j = 0; j < 4; ++j) {
            float v = rs[j];
            v += __shfl_xor(v, 1);
            v += __shfl_xor(v, 2);
            v += __shfl_xor(v, 4);
            v += __shfl_xor(v, 8);
            if (row0 == 0) spart[wq * TT + wr * 32 + m * 16 + kg * 4 + j] = v;
        }
    }
    __syncthreads();
    if (tid < TT) {
        float s = spart[0 * TT + tid] + spart[1 * TT + tid]
                + spart[2 * TT + tid] + spart[3 * TT + tid];
        scores[b * T_ + t0 + tid] = s;
    }
}

// ---------------- softmax over T per batch; fp32 alignment into d_out ----------------
__global__ __launch_bounds__(256) void softmax_k(
    const float* __restrict__ scores, float* __restrict__ out_align) {
    int b = blockIdx.x;
    int tid = threadIdx.x;
    __shared__ float redm[4];
    __shared__ float reds[4];
    float local[16];
    float mx = -1e30f;
    #pragma unroll
    for (int i = 0; i < 16; ++i) {
        float s = scores[b * T_ + tid + i * 256];
        local[i] = s;
        mx = fmaxf(mx, s);
    }
    for (int off = 32; off >= 1; off >>= 1) mx = fmaxf(mx, __shfl_xor(mx, off));
    if ((tid & 63) == 0) redm[tid >> 6] = mx;
    __syncthreads();
    mx = fmaxf(fmaxf(redm[0], redm[1]), fmaxf(redm[2], redm[3]));
    float sum = 0.f;
    #pragma unroll
    for (int i = 0; i < 16; ++i) { local[i] = __expf(local[i] - mx); sum += local[i]; }
    for (int off = 32; off >= 1; off >>= 1) sum += __shfl_xor(sum, off);
    if ((tid & 63) == 0) reds[tid >> 6] = sum;
    __syncthreads();
    sum = reds[0] + reds[1] + reds[2] + reds[3];
    float inv = 1.0f / sum;
    #pragma unroll
    for (int i = 0; i < 16; ++i)
        out_align[b * T_ + tid + i * 256] = local[i] * inv;
}

// ---------------- pout[b,chunk,h] = sum_{t in chunk} alpha * enc ----------------
__global__ __launch_bounds__(512) void pout_k(
    const float* __restrict__ enc, const float* __restrict__ alpha,
    float* __restrict__ pout) {
    int chunk = blockIdx.x;   // 0..7 (512 rows each)
    int b = blockIdx.y;
    int tid = threadIdx.x;
    int t0 = chunk * 512;
    __shared__ float as[512];
    as[tid] = alpha[b * T_ + t0 + tid];
    __syncthreads();
    float acc = 0.f;
    const float* ep = enc + ((size_t)b * T_ + t0) * H_ + tid;
    #pragma unroll 4
    for (int t = 0; t < 512; ++t) acc += as[t] * ep[(size_t)t * H_];
    pout[((size_t)b * 8 + chunk) * H_ + tid] = acc;
}

__global__ __launch_bounds__(512) void combine_k(
    const float* __restrict__ pout, float* __restrict__ out) {
    int b = blockIdx.x; int h = threadIdx.x;
    float s = 0.f;
    #pragma unroll
    for (int c = 0; c < 8; ++c) s += pout[((size_t)b * 8 + c) * H_ + h];
    out[b * H_ + h] = s;
}

extern "C" void kernel_launch(void* const* d_in, const int* in_sizes, int n_in,
                              void* d_out, int out_size, void* d_ws, size_t ws_size,
                              hipStream_t stream) {
    const float* dec    = (const float*)d_in[0];
    const float* enc    = (const float*)d_in[1];
    const float* align  = (const float*)d_in[2];
    const float* conv_w = (const float*)d_in[3];
    const float* conv_b = (const float*)d_in[4];
    const float* W      = (const float*)d_in[5];
    const float* V      = (const float*)d_in[6];
    const float* U      = (const float*)d_in[7];
    const float* bvec   = (const float*)d_in[8];
    const float* wvec   = (const float*)d_in[9];
    float* out       = (float*)d_out;           // output[B,H] fp32
    float* out_align = out + B_ * H_;           // alignment[B,T] fp32

    char* ws = (char*)d_ws;
    float*  dpb    = (float*)(ws);                   // 64 KB
    float*  scores = (float*)(ws + (64 << 10));      // 512 KB
    float*  pout   = (float*)(ws + (576 << 10));     // 512 KB
    __bf16* Vsall  = (__bf16*)(ws + (1088 << 10));   // 544 KB

    prep_kernel<<<(B_ * A_ + A_ * H_ + A_ * C_) / 256, 256, 0, stream>>>(
        dec, W, bvec, V, U, dpb, Vsall);
    scores_mfma<<<dim3(T_ / TT, B_), 1024, 0, stream>>>(enc, align, conv_w, conv_b,
                                                        Vsall, dpb, wvec, scores);
    softmax_k<<<B_, 256, 0, stream>>>(scores, out_align);
    pout_k<<<dim3(8, B_), 512, 0, stream>>>(enc, out_align, pout);
    combine_k<<<B_, 512, 0, stream>>>(pout, out);
}

// Round 9
// 199.876 us; speedup vs baseline: 1.8479x; 1.0173x over previous
//
#include <hip/hip_runtime.h>
#include <hip/hip_bf16.h>

#define B_ 32
#define T_ 4096
#define H_ 512
#define A_ 512
#define C_ 32
#define KTOT 544            // H + C (conv folded in as K-extension)
#define NKS  (KTOT / 32)    // 17 MFMA k-steps
#define TT   64             // t-tile rows per block

typedef float f32x4 __attribute__((ext_vector_type(4)));
typedef __bf16 bf16x8 __attribute__((ext_vector_type(8)));

__device__ inline float fast_tanh(float x) {
    // tanh(x) = 1 - 2/(exp(2x)+1); exact at saturation, |err| ~1e-7
    float t = __expf(2.0f * x);
    return 1.0f - 2.0f / (t + 1.0f);
}

__device__ __forceinline__ void async16(const void* g, void* l) {
    __builtin_amdgcn_global_load_lds(
        (const __attribute__((address_space(1))) unsigned int*)g,
        (__attribute__((address_space(3))) unsigned int*)l, 16, 0, 0);
}

// ---------------- prep: dpb = dec@W^T + b ; V,U -> unified bf16 fragment buffer ----
// Vsall[(k>>3)*A + a]*8 + (k&7), k in [0,544). Per-kstep 32KB chunk contiguous.
__global__ __launch_bounds__(256) void prep_kernel(
    const float* __restrict__ dec, const float* __restrict__ W,
    const float* __restrict__ bvec, const float* __restrict__ V,
    const float* __restrict__ U,
    float* __restrict__ dpb, __bf16* __restrict__ Vsall) {
    int id = blockIdx.x * 256 + threadIdx.x;
    const int N1 = B_ * A_;          // 16384
    const int N2 = A_ * H_;          // 262144
    if (id < N1) {
        int b = id / A_, a = id % A_;
        const float* dr = dec + b * H_;
        const float* wr = W + (size_t)a * H_;
        float s = 0.f;
        #pragma unroll 8
        for (int h = 0; h < H_; ++h) s += dr[h] * wr[h];
        dpb[id] = s + bvec[a];
    } else if (id < N1 + N2) {
        int e = id - N1;
        int a = e >> 9, k = e & 511;
        Vsall[((k >> 3) * A_ + a) * 8 + (k & 7)] = (__bf16)V[(size_t)a * H_ + k];
    } else {
        int e = id - N1 - N2;        // 16384 U elements
        int a = e >> 5, c = e & 31;
        int k = H_ + c;
        Vsall[((k >> 3) * A_ + a) * 8 + (k & 7)] = (__bf16)U[a * C_ + c];
    }
}

// ---------------- fused scores: 64x512 tile, dual-dbuf, 8 waves, 2 blocks/CU ----
// wave wid: wq = wid&3 -> 128-col quarter, wr = wid>>2 -> 32-row half.
// A LDS unit u = row*4 + kgl (u<256), swizzled g = u ^ ((u>>4)&7), 16B units.
__global__ __launch_bounds__(512) void scores_mfma(
    const float* __restrict__ enc, const float* __restrict__ align,
    const float* __restrict__ conv_w, const float* __restrict__ conv_b,
    const __bf16* __restrict__ Vsall, const float* __restrict__ dpb,
    const float* __restrict__ wvec, float* __restrict__ scores) {
    const int t0 = blockIdx.x * TT;
    const int b  = blockIdx.y;
    const int tid = threadIdx.x;
    const int lane = tid & 63, wid = tid >> 6;
    const int row0 = lane & 15;   // C/D col lane
    const int kg   = lane >> 4;   // k-group 0..3 within the 32-k step
    const int wq   = wid & 3;     // col quarter
    const int wr   = wid >> 2;    // row half (32 rows)
    const int wcol = wq * 128;

    __shared__ char smem[73728];  // A dbuf 2x4KB @0, B dbuf 2x32KB @8192
    float* spart = (float*)smem;  // [4][TT] = 1KB, aliases A after the loop

    const float* encb = enc + ((size_t)b * T_ + t0) * H_;
    const int arow = tid >> 2, akgl = tid & 3;   // A staging assignment (tid<256)

    // ---- stage kstep 0 ----
    {
        __bf16* bdst = (__bf16*)(smem + 8192);
        #pragma unroll
        for (int i = 0; i < 4; ++i) {
            int u = i * 512 + tid;
            async16(Vsall + u * 8, bdst + u * 8);
        }
    }
    if (tid < 256) {
        const float* p = encb + arow * H_ + akgl * 8;
        f32x4 lo = *reinterpret_cast<const f32x4*>(p);
        f32x4 hi = *reinterpret_cast<const f32x4*>(p + 4);
        bf16x8 v;
        v[0] = (__bf16)lo.x; v[1] = (__bf16)lo.y; v[2] = (__bf16)lo.z; v[3] = (__bf16)lo.w;
        v[4] = (__bf16)hi.x; v[5] = (__bf16)hi.y; v[6] = (__bf16)hi.z; v[7] = (__bf16)hi.w;
        int g = tid ^ ((tid >> 4) & 7);
        *reinterpret_cast<bf16x8*>((__bf16*)smem + g * 8) = v;
    }
    __syncthreads();

    f32x4 acc[2][8];
    #pragma unroll
    for (int m = 0; m < 2; ++m)
        #pragma unroll
        for (int n = 0; n < 8; ++n) acc[m][n] = (f32x4){0.f, 0.f, 0.f, 0.f};

    int cur = 0;
    for (int ks = 0; ks < NKS; ++ks) {
        __bf16* Acur = (__bf16*)(smem + (cur ? 4096 : 0));
        __bf16* Anxt = (__bf16*)(smem + (cur ? 0 : 4096));
        __bf16* Bcur = (__bf16*)(smem + 8192 + (cur ? 32768 : 0));
        __bf16* Bnxt = (__bf16*)(smem + 8192 + (cur ? 0 : 32768));

        f32x4 alo, ahi;
        bool stage = (ks + 1 < NKS);
        bool conv_step = (ks + 1 == NKS - 1);
        if (stage) {
            // B: async direct to LDS
            const __bf16* vchunk = Vsall + (size_t)(ks + 1) * (4 * A_ * 8);
            #pragma unroll
            for (int i = 0; i < 4; ++i) {
                int u = i * 512 + tid;
                async16(vchunk + u * 8, Bnxt + u * 8);
            }
            // A: global -> regs (issue early; consumed after compute)
            if (tid < 256 && !conv_step) {
                const float* p = encb + arow * H_ + (ks + 1) * 32 + akgl * 8;
                alo = *reinterpret_cast<const f32x4*>(p);
                ahi = *reinterpret_cast<const f32x4*>(p + 4);
            }
        }

        // ---- compute current k-step ----
        bf16x8 afrag[2];
        #pragma unroll
        for (int m = 0; m < 2; ++m) {
            int row = wr * 32 + m * 16 + row0;
            int u = row * 4 + kg;
            int g = u ^ ((u >> 4) & 7);
            afrag[m] = *reinterpret_cast<const bf16x8*>(Acur + g * 8);
        }
        const __bf16* bp = Bcur + kg * (A_ * 8);
        #pragma unroll
        for (int n = 0; n < 8; ++n) {
            bf16x8 bfrag = *reinterpret_cast<const bf16x8*>(bp + (wcol + n * 16 + row0) * 8);
            acc[0][n] = __builtin_amdgcn_mfma_f32_16x16x32_bf16(afrag[0], bfrag, acc[0][n], 0, 0, 0);
            acc[1][n] = __builtin_amdgcn_mfma_f32_16x16x32_bf16(afrag[1], bfrag, acc[1][n], 0, 0, 0);
        }

        // ---- write A-next to LDS ----
        if (stage && tid < 256) {
            bf16x8 v;
            if (!conv_step) {
                v[0] = (__bf16)alo.x; v[1] = (__bf16)alo.y; v[2] = (__bf16)alo.z; v[3] = (__bf16)alo.w;
                v[4] = (__bf16)ahi.x; v[5] = (__bf16)ahi.y; v[6] = (__bf16)ahi.z; v[7] = (__bf16)ahi.w;
            } else {
                // conv_feat k-extension: k = 512 + akgl*8 + e  ->  channel c
                int t = t0 + arow;
                float x0 = (t > 0) ? align[b * T_ + t - 1] : 0.f;
                float x1 = align[b * T_ + t];
                float x2 = (t + 1 < T_) ? align[b * T_ + t + 1] : 0.f;
                #pragma unroll
                for (int e = 0; e < 8; ++e) {
                    int c = akgl * 8 + e;
                    v[e] = (__bf16)(conv_b[c] + conv_w[c * 3 + 0] * x0
                                  + conv_w[c * 3 + 1] * x1 + conv_w[c * 3 + 2] * x2);
                }
            }
            int g = tid ^ ((tid >> 4) & 7);
            *reinterpret_cast<bf16x8*>(Anxt + g * 8) = v;
        }
        __syncthreads();   // drains B async + A ds_writes; releases cur
        cur ^= 1;
    }

    // ---- epilogue: tanh(acc + dpb)*w, reduce over A ----
    float dval[8], wv[8];
    #pragma unroll
    for (int n = 0; n < 8; ++n) {
        int a = wcol + n * 16 + row0;
        dval[n] = dpb[b * A_ + a];
        wv[n]   = wvec[a];
    }
    #pragma unroll
    for (int m = 0; m < 2; ++m) {
        float rs[4] = {0.f, 0.f, 0.f, 0.f};
        #pragma unroll
        for (int n = 0; n < 8; ++n) {
            #pragma unroll
            for (int j = 0; j < 4; ++j) {
                float x = acc[m][n][j] + dval[n];
                rs[j] += fast_tanh(x) * wv[n];
            }
        }
        #pragma unroll
        for (int j = 0; j < 4; ++j) {
            float v = rs[j];
            v += __shfl_xor(v, 1);
            v += __shfl_xor(v, 2);
            v += __shfl_xor(v, 4);
            v += __shfl_xor(v, 8);
            if (row0 == 0) spart[wq * TT + wr * 32 + m * 16 + kg * 4 + j] = v;
        }
    }
    __syncthreads();
    if (tid < TT) {
        float s = spart[0 * TT + tid] + spart[1 * TT + tid]
                + spart[2 * TT + tid] + spart[3 * TT + tid];
        scores[b * T_ + t0 + tid] = s;
    }
}

// ---------------- softmax over T per batch; fp32 alignment into d_out ----------------
__global__ __launch_bounds__(256) void softmax_k(
    const float* __restrict__ scores, float* __restrict__ out_align) {
    int b = blockIdx.x;
    int tid = threadIdx.x;
    __shared__ float redm[4];
    __shared__ float reds[4];
    float local[16];
    float mx = -1e30f;
    #pragma unroll
    for (int i = 0; i < 16; ++i) {
        float s = scores[b * T_ + tid + i * 256];
        local[i] = s;
        mx = fmaxf(mx, s);
    }
    for (int off = 32; off >= 1; off >>= 1) mx = fmaxf(mx, __shfl_xor(mx, off));
    if ((tid & 63) == 0) redm[tid >> 6] = mx;
    __syncthreads();
    mx = fmaxf(fmaxf(redm[0], redm[1]), fmaxf(redm[2], redm[3]));
    float sum = 0.f;
    #pragma unroll
    for (int i = 0; i < 16; ++i) { local[i] = __expf(local[i] - mx); sum += local[i]; }
    for (int off = 32; off >= 1; off >>= 1) sum += __shfl_xor(sum, off);
    if ((tid & 63) == 0) reds[tid >> 6] = sum;
    __syncthreads();
    sum = reds[0] + reds[1] + reds[2] + reds[3];
    float inv = 1.0f / sum;
    #pragma unroll
    for (int i = 0; i < 16; ++i)
        out_align[b * T_ + tid + i * 256] = local[i] * inv;
}

// ---------------- pout[b,chunk,h] = sum_{t in chunk} alpha * enc ----------------
__global__ __launch_bounds__(512) void pout_k(
    const float* __restrict__ enc, const float* __restrict__ alpha,
    float* __restrict__ pout) {
    int chunk = blockIdx.x;   // 0..7 (512 rows each)
    int b = blockIdx.y;
    int tid = threadIdx.x;
    int t0 = chunk * 512;
    __shared__ float as[512];
    as[tid] = alpha[b * T_ + t0 + tid];
    __syncthreads();
    float acc = 0.f;
    const float* ep = enc + ((size_t)b * T_ + t0) * H_ + tid;
    #pragma unroll 4
    for (int t = 0; t < 512; ++t) acc += as[t] * ep[(size_t)t * H_];
    pout[((size_t)b * 8 + chunk) * H_ + tid] = acc;
}

__global__ __launch_bounds__(512) void combine_k(
    const float* __restrict__ pout, float* __restrict__ out) {
    int b = blockIdx.x; int h = threadIdx.x;
    float s = 0.f;
    #pragma unroll
    for (int c = 0; c < 8; ++c) s += pout[((size_t)b * 8 + c) * H_ + h];
    out[b * H_ + h] = s;
}

extern "C" void kernel_launch(void* const* d_in, const int* in_sizes, int n_in,
                              void* d_out, int out_size, void* d_ws, size_t ws_size,
                              hipStream_t stream) {
    const float* dec    = (const float*)d_in[0];
    const float* enc    = (const float*)d_in[1];
    const float* align  = (const float*)d_in[2];
    const float* conv_w = (const float*)d_in[3];
    const float* conv_b = (const float*)d_in[4];
    const float* W      = (const float*)d_in[5];
    const float* V      = (const float*)d_in[6];
    const float* U      = (const float*)d_in[7];
    const float* bvec   = (const float*)d_in[8];
    const float* wvec   = (const float*)d_in[9];
    float* out       = (float*)d_out;           // output[B,H] fp32
    float* out_align = out + B_ * H_;           // alignment[B,T] fp32

    char* ws = (char*)d_ws;
    float*  dpb    = (float*)(ws);                   // 64 KB
    float*  scores = (float*)(ws + (64 << 10));      // 512 KB
    float*  pout   = (float*)(ws + (576 << 10));     // 512 KB
    __bf16* Vsall  = (__bf16*)(ws + (1088 << 10));   // 544 KB

    prep_kernel<<<(B_ * A_ + A_ * H_ + A_ * C_) / 256, 256, 0, stream>>>(
        dec, W, bvec, V, U, dpb, Vsall);
    scores_mfma<<<dim3(T_ / TT, B_), 512, 0, stream>>>(enc, align, conv_w, conv_b,
                                                       Vsall, dpb, wvec, scores);
    softmax_k<<<B_, 256, 0, stream>>>(scores, out_align);
    pout_k<<<dim3(8, B_), 512, 0, stream>>>(enc, out_align, pout);
    combine_k<<<B_, 512, 0, stream>>>(pout, out);
}

// Round 10
// 193.599 us; speedup vs baseline: 1.9078x; 1.0324x over previous
//
#include <hip/hip_runtime.h>
#include <hip/hip_bf16.h>

#define B_ 32
#define T_ 4096
#define H_ 512
#define A_ 512
#define C_ 32
#define KTOT 544            // H + C (conv folded in as K-extension)
#define NKS  (KTOT / 32)    // 17 MFMA k-steps
#define TT   128            // t-tile rows per block

typedef float f32x4 __attribute__((ext_vector_type(4)));
typedef __bf16 bf16x8 __attribute__((ext_vector_type(8)));
typedef __bf16 bf16x4 __attribute__((ext_vector_type(4)));

__device__ inline float fast_tanh(float x) {
    // tanh(x) = 1 - 2/(exp(2x)+1); exact at saturation, |err| ~1e-7
    float t = __expf(2.0f * x);
    return 1.0f - 2.0f / (t + 1.0f);
}

__device__ __forceinline__ void async16(const void* g, void* l) {
    __builtin_amdgcn_global_load_lds(
        (const __attribute__((address_space(1))) unsigned int*)g,
        (__attribute__((address_space(3))) unsigned int*)l, 16, 0, 0);
}

// ---------------- prep: dpb = dec@W^T + b ; V,U -> unified bf16 fragment buffer ----
// Vsall[(k>>3)*A + a]*8 + (k&7), k in [0,544). Per-kstep 32KB chunk contiguous.
__global__ __launch_bounds__(256) void prep_kernel(
    const float* __restrict__ dec, const float* __restrict__ W,
    const float* __restrict__ bvec, const float* __restrict__ V,
    const float* __restrict__ U,
    float* __restrict__ dpb, __bf16* __restrict__ Vsall) {
    int id = blockIdx.x * 256 + threadIdx.x;
    const int N1 = B_ * A_;          // 16384
    const int N2 = A_ * H_;          // 262144
    if (id < N1) {
        int b = id / A_, a = id % A_;
        const float* dr = dec + b * H_;
        const float* wr = W + (size_t)a * H_;
        float s = 0.f;
        #pragma unroll 8
        for (int h = 0; h < H_; ++h) s += dr[h] * wr[h];
        dpb[id] = s + bvec[a];
    } else if (id < N1 + N2) {
        int e = id - N1;
        int a = e >> 9, k = e & 511;
        Vsall[((k >> 3) * A_ + a) * 8 + (k & 7)] = (__bf16)V[(size_t)a * H_ + k];
    } else {
        int e = id - N1 - N2;        // 16384 U elements
        int a = e >> 5, c = e & 31;
        int k = H_ + c;
        Vsall[((k >> 3) * A_ + a) * 8 + (k & 7)] = (__bf16)U[a * C_ + c];
    }
}

// ---------------- fused scores: 128x512 tile, counted-vmcnt pipeline ----------------
// 16 waves: wq = wid&3 -> 128-col quarter, wr = wid>>2 -> 32-row quarter.
// B: 3 LDS buffers, global_load_lds issued 2 ksteps ahead.
// A: regs loaded 2 ahead (1 f32x4/thread), ds_write 1 ahead; 2 LDS buffers.
// A LDS: unit (row, kq 0..7) of 4 bf16 at byte row*64 + (kq ^ (((row>>1)&3)<<1))*8.
__global__ __launch_bounds__(1024) void scores_mfma(
    const float* __restrict__ enc, const float* __restrict__ align,
    const float* __restrict__ conv_w, const float* __restrict__ conv_b,
    const __bf16* __restrict__ Vsall, const float* __restrict__ dpb,
    const float* __restrict__ wvec, float* __restrict__ scores) {
    const int t0 = blockIdx.x * TT;
    const int b  = blockIdx.y;
    const int tid = threadIdx.x;
    const int lane = tid & 63, wid = tid >> 6;
    const int row0 = lane & 15;   // C/D col lane
    const int kg   = lane >> 4;   // k-group 0..3 within the 32-k step
    const int wq   = wid & 3;     // col quarter
    const int wr   = wid >> 2;    // row quarter (32 rows)
    const int wcol = wq * 128;

    __shared__ char smem[114688];  // A: 2x8KB @0; B: 3x32KB @16384
    float* spart = (float*)smem;   // [4][TT] = 2KB, aliases A after the loop

    const float* encb = enc + ((size_t)b * T_ + t0) * H_;
    const int arow = tid >> 3;     // 0..127
    const int akq  = tid & 7;      // 0..7
    const int aswz = ((arow >> 1) & 3) << 1;
    const int awbyte = arow * 64 + ((akq ^ aswz) << 3);

    int arbyte[2];
    #pragma unroll
    for (int m = 0; m < 2; ++m) {
        int row = wr * 32 + m * 16 + row0;
        int rs = ((row >> 1) & 3) << 1;
        arbyte[m] = row * 64 + (((kg << 1) ^ rs) << 3);
    }

    f32x4 areg[2];
    float cx0 = 0.f, cx1 = 0.f, cx2 = 0.f;

    // ---------------- prologue: B(0),B(1) async; A(0) write; A(1) regs ----------------
    #pragma unroll
    for (int s = 0; s < 2; ++s) {
        char* bdst = smem + 16384 + s * 32768;
        #pragma unroll
        for (int i = 0; i < 2; ++i) {
            int u = i * 1024 + tid;
            async16(Vsall + (size_t)s * 16384 + (size_t)u * 8, bdst + u * 16);
        }
    }
    {
        f32x4 a0 = *reinterpret_cast<const f32x4*>(encb + arow * H_ + akq * 4);
        areg[1]  = *reinterpret_cast<const f32x4*>(encb + arow * H_ + 32 + akq * 4);
        bf16x4 v;
        v[0] = (__bf16)a0.x; v[1] = (__bf16)a0.y; v[2] = (__bf16)a0.z; v[3] = (__bf16)a0.w;
        *reinterpret_cast<bf16x4*>(smem + awbyte) = v;
    }
    asm volatile("s_waitcnt vmcnt(0) lgkmcnt(0)" ::: "memory");
    __builtin_amdgcn_sched_barrier(0);
    __builtin_amdgcn_s_barrier();

    f32x4 acc[2][8];
    #pragma unroll
    for (int m = 0; m < 2; ++m)
        #pragma unroll
        for (int n = 0; n < 8; ++n) acc[m][n] = (f32x4){0.f, 0.f, 0.f, 0.f};

    // ---------------- pipelined K loop ----------------
    #pragma unroll
    for (int ks = 0; ks < NKS; ++ks) {
        // ---- issue stage for kstep ks+2 ----
        if (ks + 2 <= NKS - 1) {
            char* bdst = smem + 16384 + ((ks + 2) % 3) * 32768;
            const __bf16* src = Vsall + (size_t)(ks + 2) * 16384;
            #pragma unroll
            for (int i = 0; i < 2; ++i) {
                int u = i * 1024 + tid;
                async16(src + (size_t)u * 8, bdst + u * 16);
            }
            if (ks + 2 < NKS - 1) {
                areg[ks & 1] = *reinterpret_cast<const f32x4*>(
                    encb + arow * H_ + (ks + 2) * 32 + akq * 4);
            } else {   // ks == 14: conv inputs for A(16); exactly 3 unmasked loads
                int t = t0 + arow;
                int tm = (t > 0) ? t - 1 : 0;
                int tp = (t + 1 < T_) ? t + 1 : T_ - 1;
                cx0 = align[(size_t)b * T_ + tm];
                cx1 = align[(size_t)b * T_ + t];
                cx2 = align[(size_t)b * T_ + tp];
                if (t == 0) cx0 = 0.f;
                if (t + 1 == T_) cx2 = 0.f;
            }
        }

        // ---- compute kstep ks ----
        char* Ard = smem + (ks & 1) * 8192;
        bf16x8 afrag[2];
        #pragma unroll
        for (int m = 0; m < 2; ++m)
            afrag[m] = *reinterpret_cast<const bf16x8*>(Ard + arbyte[m]);
        const __bf16* bp = (const __bf16*)(smem + 16384 + (ks % 3) * 32768) + kg * (A_ * 8);
        #pragma unroll
        for (int n = 0; n < 8; ++n) {
            bf16x8 bfrag = *reinterpret_cast<const bf16x8*>(bp + (wcol + n * 16 + row0) * 8);
            acc[0][n] = __builtin_amdgcn_mfma_f32_16x16x32_bf16(afrag[0], bfrag, acc[0][n], 0, 0, 0);
            acc[1][n] = __builtin_amdgcn_mfma_f32_16x16x32_bf16(afrag[1], bfrag, acc[1][n], 0, 0, 0);
        }

        // ---- write A(ks+1) to the other A buffer ----
        if (ks + 1 <= NKS - 1) {
            bf16x4 v;
            if (ks + 1 < NKS - 1) {
                f32x4 a = areg[(ks + 1) & 1];
                v[0] = (__bf16)a.x; v[1] = (__bf16)a.y; v[2] = (__bf16)a.z; v[3] = (__bf16)a.w;
            } else {   // ks == 15: A(16) = conv_feat k-extension
                #pragma unroll
                for (int e = 0; e < 4; ++e) {
                    int c = akq * 4 + e;
                    v[e] = (__bf16)(conv_b[c] + conv_w[c * 3] * cx0
                                  + conv_w[c * 3 + 1] * cx1 + conv_w[c * 3 + 2] * cx2);
                }
            }
            char* Adst = smem + ((ks + 1) & 1) * 8192;
            *reinterpret_cast<bf16x4*>(Adst + awbyte) = v;
        }

        // ---- counted-drain barrier (never vmcnt(0) in steady state) ----
        if (ks < 14) {
            asm volatile("s_waitcnt vmcnt(3) lgkmcnt(0)" ::: "memory");
        } else if (ks == 14) {
            asm volatile("s_waitcnt vmcnt(5) lgkmcnt(0)" ::: "memory");
        } else if (ks == 15) {
            asm volatile("s_waitcnt vmcnt(0) lgkmcnt(0)" ::: "memory");
        }
        if (ks < NKS - 1) {
            __builtin_amdgcn_sched_barrier(0);
            __builtin_amdgcn_s_barrier();
        }
    }
    __syncthreads();   // full drain once; spart aliases A buffers below

    // ---- epilogue: tanh(acc + dpb)*w, reduce over A ----
    float dval[8], wv[8];
    #pragma unroll
    for (int n = 0; n < 8; ++n) {
        int a = wcol + n * 16 + row0;
        dval[n] = dpb[b * A_ + a];
        wv[n]   = wvec[a];
    }
    #pragma unroll
    for (int m = 0; m < 2; ++m) {
        float rs[4] = {0.f, 0.f, 0.f, 0.f};
        #pragma unroll
        for (int n = 0; n < 8; ++n) {
            #pragma unroll
            for (int j = 0; j < 4; ++j) {
                float x = acc[m][n][j] + dval[n];
                rs[j] += fast_tanh(x) * wv[n];
            }
        }
        #pragma unroll
        for (int j = 0; j < 4; ++j) {
            float v = rs[j];
            v += __shfl_xor(v, 1);
            v += __shfl_xor(v, 2);
            v += __shfl_xor(v, 4);
            v += __shfl_xor(v, 8);
            if (row0 == 0) spart[wq * TT + wr * 32 + m * 16 + kg * 4 + j] = v;
        }
    }
    __syncthreads();
    if (tid < TT) {
        float s = spart[0 * TT + tid] + spart[1 * TT + tid]
                + spart[2 * TT + tid] + spart[3 * TT + tid];
        scores[b * T_ + t0 + tid] = s;
    }
}

// ---------------- softmax over T per batch; fp32 alignment into d_out ----------------
__global__ __launch_bounds__(256) void softmax_k(
    const float* __restrict__ scores, float* __restrict__ out_align) {
    int b = blockIdx.x;
    int tid = threadIdx.x;
    __shared__ float redm[4];
    __shared__ float reds[4];
    float local[16];
    float mx = -1e30f;
    #pragma unroll
    for (int i = 0; i < 16; ++i) {
        float s = scores[b * T_ + tid + i * 256];
        local[i] = s;
        mx = fmaxf(mx, s);
    }
    for (int off = 32; off >= 1; off >>= 1) mx = fmaxf(mx, __shfl_xor(mx, off));
    if ((tid & 63) == 0) redm[tid >> 6] = mx;
    __syncthreads();
    mx = fmaxf(fmaxf(redm[0], redm[1]), fmaxf(redm[2], redm[3]));
    float sum = 0.f;
    #pragma unroll
    for (int i = 0; i < 16; ++i) { local[i] = __expf(local[i] - mx); sum += local[i]; }
    for (int off = 32; off >= 1; off >>= 1) sum += __shfl_xor(sum, off);
    if ((tid & 63) == 0) reds[tid >> 6] = sum;
    __syncthreads();
    sum = reds[0] + reds[1] + reds[2] + reds[3];
    float inv = 1.0f / sum;
    #pragma unroll
    for (int i = 0; i < 16; ++i)
        out_align[b * T_ + tid + i * 256] = local[i] * inv;
}

// ---------------- pout[b,chunk,h] = sum_{t in chunk} alpha * enc ----------------
__global__ __launch_bounds__(512) void pout_k(
    const float* __restrict__ enc, const float* __restrict__ alpha,
    float* __restrict__ pout) {
    int chunk = blockIdx.x;   // 0..7 (512 rows each)
    int b = blockIdx.y;
    int tid = threadIdx.x;
    int t0 = chunk * 512;
    __shared__ float as[512];
    as[tid] = alpha[b * T_ + t0 + tid];
    __syncthreads();
    float acc = 0.f;
    const float* ep = enc + ((size_t)b * T_ + t0) * H_ + tid;
    #pragma unroll 4
    for (int t = 0; t < 512; ++t) acc += as[t] * ep[(size_t)t * H_];
    pout[((size_t)b * 8 + chunk) * H_ + tid] = acc;
}

__global__ __launch_bounds__(512) void combine_k(
    const float* __restrict__ pout, float* __restrict__ out) {
    int b = blockIdx.x; int h = threadIdx.x;
    float s = 0.f;
    #pragma unroll
    for (int c = 0; c < 8; ++c) s += pout[((size_t)b * 8 + c) * H_ + h];
    out[b * H_ + h] = s;
}

extern "C" void kernel_launch(void* const* d_in, const int* in_sizes, int n_in,
                              void* d_out, int out_size, void* d_ws, size_t ws_size,
                              hipStream_t stream) {
    const float* dec    = (const float*)d_in[0];
    const float* enc    = (const float*)d_in[1];
    const float* align  = (const float*)d_in[2];
    const float* conv_w = (const float*)d_in[3];
    const float* conv_b = (const float*)d_in[4];
    const float* W      = (const float*)d_in[5];
    const float* V      = (const float*)d_in[6];
    const float* U      = (const float*)d_in[7];
    const float* bvec   = (const float*)d_in[8];
    const float* wvec   = (const float*)d_in[9];
    float* out       = (float*)d_out;           // output[B,H] fp32
    float* out_align = out + B_ * H_;           // alignment[B,T] fp32

    char* ws = (char*)d_ws;
    float*  dpb    = (float*)(ws);                   // 64 KB
    float*  scores = (float*)(ws + (64 << 10));      // 512 KB
    float*  pout   = (float*)(ws + (576 << 10));     // 512 KB
    __bf16* Vsall  = (__bf16*)(ws + (1088 << 10));   // 544 KB

    prep_kernel<<<(B_ * A_ + A_ * H_ + A_ * C_) / 256, 256, 0, stream>>>(
        dec, W, bvec, V, U, dpb, Vsall);
    scores_mfma<<<dim3(T_ / TT, B_), 1024, 0, stream>>>(enc, align, conv_w, conv_b,
                                                        Vsall, dpb, wvec, scores);
    softmax_k<<<B_, 256, 0, stream>>>(scores, out_align);
    pout_k<<<dim3(8, B_), 512, 0, stream>>>(enc, out_align, pout);
    combine_k<<<B_, 512, 0, stream>>>(pout, out);
}